// Round 5
// baseline (470.900 us; speedup 1.0000x reference)
//
#include <hip/hip_runtime.h>

// PatchMatch propagation, B=2, H=W=64, corr (B,H,W,H,W) f32.
// Anti-diagonal wavefront, one wave per batch; lane r owns sweep-row r.
// R5: 3-way SPECULATIVE PREFETCH. A pixel's final coords are one of
// {pC (keep, score memoized), vC, hC}. At step d each lane issues tap loads
// for step d+1's candidates under all 3 possible own-carries (h side) and
// all 3 possible neighbor-carries (v side, via shfl). At step d+1 a 2-bit
// selector picks the pre-loaded taps -> global-load latency leaves the
// dependent chain. Invalid speculation paths are never selectable because
// the reference's own r>0 / c>0 guards constrain the selector.

struct __attribute__((packed, aligned(4))) f2u { float x, y; };

__device__ __forceinline__ float clamp63(float v) {
    return fminf(fmaxf(v, 0.0f), 63.0f);
}

__device__ __forceinline__ float sel3f(int s, float a0, float a1, float a2) {
    float r = (s == 1) ? a1 : a0;
    return (s == 2) ? a2 : r;
}

// Full bilinear sample (init / random-search phases), bit-exact vs reference.
__device__ __forceinline__ float bsample(const float* __restrict__ m, float x, float y) {
    float x0f = floorf(x), y0f = floorf(y);
    float wx1 = __fsub_rn(x, x0f);
    float wy1 = __fsub_rn(y, y0f);
    float wx0 = __fsub_rn(1.0f, wx1);
    float wy0 = __fsub_rn(1.0f, wy1);
    int x0 = (int)x0f, y0 = (int)y0f;
    int x1 = x0 + 1, y1 = y0 + 1;
    int y1c = min(y1, 63);
    int bx = min(x0, 62);
    f2u p0 = *(const f2u*)(m + y0 * 64 + bx);
    f2u p1 = *(const f2u*)(m + y1c * 64 + bx);
    bool hi = (x0 > 62);
    float v00 = hi ? p0.y : p0.x;
    float v10 = (x1 <= 63) ? p0.y : 0.0f;
    float v01 = hi ? p1.y : p1.x;
    v01 = (y1 <= 63) ? v01 : 0.0f;
    float v11 = ((x1 <= 63) && (y1 <= 63)) ? p1.y : 0.0f;
    float t0 = __fmul_rn(__fmul_rn(wx0, wy0), v00);
    float t1 = __fmul_rn(__fmul_rn(wx1, wy0), v10);
    float t2 = __fmul_rn(__fmul_rn(wx0, wy1), v01);
    float t3 = __fmul_rn(__fmul_rn(wx1, wy1), v11);
    return __fadd_rn(__fadd_rn(__fadd_rn(t0, t1), t2), t3);
}

// Score from pre-loaded pair taps at coords (x,y); taps were loaded with
// bx=min(floor(x),62), rows floor(y) and min(floor(y)+1,63) of the SAME coords.
__device__ __forceinline__ float score_taps(float x, float y, f2u p0, f2u p1) {
    float x0f = floorf(x), y0f = floorf(y);
    float wx1 = __fsub_rn(x, x0f);
    float wy1 = __fsub_rn(y, y0f);
    float wx0 = __fsub_rn(1.0f, wx1);
    float wy0 = __fsub_rn(1.0f, wy1);
    int x0 = (int)x0f, y0 = (int)y0f;
    int x1 = x0 + 1, y1 = y0 + 1;
    bool hi = (x0 > 62);
    float v00 = hi ? p0.y : p0.x;
    float v10 = (x1 <= 63) ? p0.y : 0.0f;
    float v01 = hi ? p1.y : p1.x;
    v01 = (y1 <= 63) ? v01 : 0.0f;
    float v11 = ((x1 <= 63) && (y1 <= 63)) ? p1.y : 0.0f;
    float t0 = __fmul_rn(__fmul_rn(wx0, wy0), v00);
    float t1 = __fmul_rn(__fmul_rn(wx1, wy0), v10);
    float t2 = __fmul_rn(__fmul_rn(wx0, wy1), v01);
    float t3 = __fmul_rn(__fmul_rn(wx1, wy1), v11);
    return __fadd_rn(__fadd_rn(__fadd_rn(t0, t1), t2), t3);
}

__device__ __forceinline__ void tapload(const float* __restrict__ m, float x, float y,
                                        f2u& A, f2u& B) {
    int x0 = (int)floorf(x);
    int y0 = (int)floorf(y);
    int bx = min(x0, 62);
    int y1c = min(y0 + 1, 63);
    A = *(const f2u*)(m + y0 * 64 + bx);
    B = *(const f2u*)(m + y1c * 64 + bx);
}

// Speculative bank: candidate coords + their pair-taps for one pixel.
struct Bank {
    float hx0, hy0, hx1, hy1, hx2, hy2;   // h-candidate under own-carry {p,v,h}
    float vx0, vy0, vx1, vy1, vx2, vy2;   // v-candidate under nbr-carry {p,v,h}
    f2u hA0, hB0, hA1, hB1, hA2, hB2;
    f2u vA0, vB0, vA1, vB1, vA2, vB2;
};

__global__ __launch_bounds__(1024, 1) void MatchingPropagator_65180423685702_kernel(
        const float* __restrict__ raw,    // (B,2,64,64)
        const float* __restrict__ corr,   // (B,64,64,64,64)
        const float* __restrict__ noise,  // (3,B,64,64,2)
        float* __restrict__ out) {        // (B,2,64,64)
    const int b = blockIdx.x;
    const float* __restrict__ corrb = corr + (size_t)b * 64 * 64 * 4096;
    const int tid = threadIdx.x;

    __shared__ float lx[4096];
    __shared__ float ly[4096];
    __shared__ float ls[4096];

    // init: coords + memoized scores (parallel)
    for (int p = tid; p < 4096; p += blockDim.x) {
        float x = raw[(size_t)b * 8192 + p];
        float y = raw[(size_t)b * 8192 + 4096 + p];
        lx[p] = x; ly[p] = y;
        ls[p] = bsample(corrb + (size_t)p * 4096, x, y);
    }
    __syncthreads();

    const int dys[4] = {1, -1, -1, 1};
    const int dxs[4] = {1, -1, 1, -1};

#pragma unroll
    for (int k = 0; k < 4; ++k) {
        const int dy = dys[k], dx = dxs[k];
        const float fdy = (float)dy, fdx = (float)dx;
        const bool dxpos = (dx > 0);

        if (tid < 64) {
            const int r = tid;
            const int i = (dy > 0) ? r : 63 - r;
            const float* rowbase = corrb + (size_t)i * 64 * 4096;
            int sme = 0;                  // selector of previous resolve: 0=p,1=v,2=h
            Bank bA = {}, bB = {};

            // prefetch for pixel c_next, given my 3 possible carries (K).
            auto prefetch = [&](int cnext, float kx0, float ky0, float kx1, float ky1,
                                float kx2, float ky2, Bank& o) {
                // neighbor's possible carries via shfl (lane r-1's K)
                float nx0 = __shfl_up(kx0, 1), ny0 = __shfl_up(ky0, 1);
                float nx1 = __shfl_up(kx1, 1), ny1 = __shfl_up(ky1, 1);
                float nx2 = __shfl_up(kx2, 1), ny2 = __shfl_up(ky2, 1);
                o.hx0 = clamp63(__fadd_rn(kx0, fdx)); o.hy0 = clamp63(ky0);
                o.hx1 = clamp63(__fadd_rn(kx1, fdx)); o.hy1 = clamp63(ky1);
                o.hx2 = clamp63(__fadd_rn(kx2, fdx)); o.hy2 = clamp63(ky2);
                o.vx0 = clamp63(nx0); o.vy0 = clamp63(__fadd_rn(ny0, fdy));
                o.vx1 = clamp63(nx1); o.vy1 = clamp63(__fadd_rn(ny1, fdy));
                o.vx2 = clamp63(nx2); o.vy2 = clamp63(__fadd_rn(ny2, fdy));
                int cn = min(max(cnext, 0), 63);
                int jn = dxpos ? cn : 63 - cn;
                const float* m = rowbase + (size_t)jn * 4096;
                if ((cnext >= 0) && (cnext < 64)) {
                    tapload(m, o.hx0, o.hy0, o.hA0, o.hB0);
                    tapload(m, o.hx1, o.hy1, o.hA1, o.hB1);
                    tapload(m, o.hx2, o.hy2, o.hA2, o.hB2);
                    tapload(m, o.vx0, o.vy0, o.vA0, o.vB0);
                    tapload(m, o.vx1, o.vy1, o.vA1, o.vB1);
                    tapload(m, o.vx2, o.vy2, o.vA2, o.vB2);
                }
            };

            auto step = [&](int d, const Bank& in, Bank& o) {
                const int c = d - r;
                const bool act = (c >= 0) && (c < 64);
                const int cc = min(max(c, 0), 63);
                const int j = dxpos ? cc : 63 - cc;
                const int p = i * 64 + j;
                // neighbor's selector from its previous resolve
                int snb = __shfl_up(sme, 1);
                // own pre-sweep state (memoized score!)
                float px = lx[p], py = ly[p], ps = ls[p];
                // resolve actual candidates from speculation banks
                float hcx = sel3f(sme, in.hx0, in.hx1, in.hx2);
                float hcy = sel3f(sme, in.hy0, in.hy1, in.hy2);
                float vcx = sel3f(snb, in.vx0, in.vx1, in.vx2);
                float vcy = sel3f(snb, in.vy0, in.vy1, in.vy2);
                // issue NEXT step's speculative loads ASAP (K = {pC, vC, hC})
                prefetch(c + 1, px, py, vcx, vcy, hcx, hcy, o);
                // select the pre-loaded taps
                f2u HA, HB, VA, VB;
                HA.x = sel3f(sme, in.hA0.x, in.hA1.x, in.hA2.x);
                HA.y = sel3f(sme, in.hA0.y, in.hA1.y, in.hA2.y);
                HB.x = sel3f(sme, in.hB0.x, in.hB1.x, in.hB2.x);
                HB.y = sel3f(sme, in.hB0.y, in.hB1.y, in.hB2.y);
                VA.x = sel3f(snb, in.vA0.x, in.vA1.x, in.vA2.x);
                VA.y = sel3f(snb, in.vA0.y, in.vA1.y, in.vA2.y);
                VB.x = sel3f(snb, in.vB0.x, in.vB1.x, in.vB2.x);
                VB.y = sel3f(snb, in.vB0.y, in.vB1.y, in.vB2.y);
                float hs = score_taps(hcx, hcy, HA, HB);
                float vs = score_taps(vcx, vcy, VA, VB);
                // reference resolve order: vertical first, then horizontal
                bool uv = (vs > ps) && (r > 0);
                float ux = uv ? vcx : px;
                float uy = uv ? vcy : py;
                float us = uv ? vs : ps;
                bool uh = (hs > us) && (c > 0);
                float fx = uh ? hcx : ux;
                float fy = uh ? hcy : uy;
                float fs = uh ? hs : us;
                sme = uh ? 2 : (uv ? 1 : 0);
                if (act) { lx[p] = fx; ly[p] = fy; ls[p] = fs; }
            };

            // prologue: speculate for d=0 with K = {(0,0)x3} (matches carry init)
            prefetch(0 - r, 0.0f, 0.0f, 0.0f, 0.0f, 0.0f, 0.0f, bA);
#pragma unroll 1
            for (int d = 0; d < 128; d += 2) {
                step(d, bA, bB);
                step(d + 1, bB, bA);
            }
        }
        __syncthreads();

        // random search (elementwise, all 1024 threads)
        if (k < 3) {
            const float* nz = noise + ((size_t)k * 2 + b) * 8192;
            for (int p = tid; p < 4096; p += blockDim.x) {
                float x = lx[p], y = ly[p], s = ls[p];
                float ex = nz[p * 2 + 0], ey = nz[p * 2 + 1];
                float nx = fmaxf(__fadd_rn(x, __fmul_rn(3.0f, ex)), 0.0f);
                float ny = fmaxf(__fadd_rn(y, __fmul_rn(3.0f, ey)), 0.0f);
                // faithful reference oddity: boundary hit overwrites BOTH channels
                if (nx >= 64.0f) { nx = 63.0f; ny = 63.0f; }
                if (ny >= 64.0f) { nx = 63.0f; ny = 63.0f; }
                float ns = bsample(corrb + (size_t)p * 4096, nx, ny);
                if (ns > __fmul_rn(1.05f, s)) {
                    lx[p] = nx; ly[p] = ny; ls[p] = ns;
                }
            }
            __syncthreads();
        }
    }

    // output: (B,2,H,W)
    for (int p = tid; p < 4096; p += blockDim.x) {
        out[(size_t)b * 8192 + p] = lx[p];
        out[(size_t)b * 8192 + 4096 + p] = ly[p];
    }
}

extern "C" void kernel_launch(void* const* d_in, const int* in_sizes, int n_in,
                              void* d_out, int out_size, void* d_ws, size_t ws_size,
                              hipStream_t stream) {
    const float* raw   = (const float*)d_in[0];
    const float* corr  = (const float*)d_in[1];
    const float* noise = (const float*)d_in[2];
    float* out = (float*)d_out;
    (void)in_sizes; (void)n_in; (void)out_size; (void)d_ws; (void)ws_size;
    MatchingPropagator_65180423685702_kernel<<<2, 1024, 0, stream>>>(raw, corr, noise, out);
}